// Round 13
// baseline (1229.443 us; speedup 1.0000x reference)
//
#include <hip/hip_runtime.h>
#include <math.h>

// Sizes (fixed): B=32, T=100, S=100, H=512, E=256, V=30000, 4H=2048, M_log=3168

typedef __attribute__((ext_vector_type(8))) short short8v;  // 8 bf16 (4 VGPRs)
typedef __attribute__((ext_vector_type(4))) float f32x4;
typedef unsigned long long ull;

#define LSTM_BLOCKS 64
#define NTIL 235

__device__ __forceinline__ float sigf(float x){ return 1.0f/(1.0f + __expf(-x)); }
__device__ __forceinline__ float tanhc(float x){
  x = fminf(fmaxf(x, -15.f), 15.f);
  float e = __expf(2.f*x);
  return (e-1.f)/(e+1.f);
}
__device__ __forceinline__ short f2bf(float f){
  unsigned u = __float_as_uint(f);
  u = (u + 0x7fffu + ((u >> 16) & 1u)) >> 16;
  return (short)u;
}
__device__ __forceinline__ float bf2f(short s){
  return __uint_as_float(((unsigned)(unsigned short)s) << 16);
}

// frag-ordered hq element offset for h[b][u0..u0+7] (u0 % 8 == 0), within one l:
//   (u>>5)*1024 + (b>>4)*512 + ((u>>3)&3)*128 + (b&15)*8
__device__ __forceinline__ long hq_elem(int t, int l, int b, int u0){
  return (long)(t+1)*32768 + (long)l*16384
       + (u0 >> 5)*1024 + (b >> 4)*512 + ((u0 >> 3) & 3)*128 + (b & 15)*8;
}

// ---------------------------------------------------------------------------
// prep: gate-permuted weights for BOTH LSTMs (blockIdx.y selects).
// ---------------------------------------------------------------------------
__global__ void prep_permute(
    const float* __restrict__ Wi_e, const float* __restrict__ Wh_e,
    const float* __restrict__ bi_e, const float* __restrict__ bh_e,
    const float* __restrict__ Wi_w, const float* __restrict__ Wh_w,
    const float* __restrict__ bi_w, const float* __restrict__ bh_w,
    short* __restrict__ WiPh_e, short* __restrict__ WhPh_e, float* __restrict__ biasP_e,
    short* __restrict__ WiPh_w, short* __restrict__ WhPh_w, float* __restrict__ biasP_w)
{
  const int z = blockIdx.y;
  const float* Wi = z ? Wi_w : Wi_e;
  const float* Wh = z ? Wh_w : Wh_e;
  const float* bi = z ? bi_w : bi_e;
  const float* bh = z ? bh_w : bh_e;
  short* WiPh = z ? WiPh_w : WiPh_e;
  short* WhPh = z ? WhPh_w : WhPh_e;
  float* biasP = z ? biasP_w : biasP_e;

  int idx = blockIdx.x*256 + threadIdx.x;      // 0 .. 1048575
  {
    int op = idx >> 9, k = idx & 511;
    int u = op >> 2, g = op & 3;
    WhPh[idx] = f2bf(Wh[(g*512+u)*512 + k]);
  }
  if (idx < 2048*256) {
    int op = idx >> 8, e = idx & 255;
    int u = op >> 2, g = op & 3;
    WiPh[idx] = f2bf(Wi[(g*512+u)*256 + e]);
  }
  if (idx < 2048) {
    int u = idx >> 2, g = idx & 3;
    biasP[idx] = bi[g*512+u] + bh[g*512+u];
  }
}

// ---------------------------------------------------------------------------
// misc prep: emb->bf16, conv Wp, conv Wm, h0 -> hq[0] (frag order), flags,
// edit counters
// ---------------------------------------------------------------------------
__global__ void misc_prep(const float* __restrict__ emb,
                          const float* __restrict__ Wp, const float* __restrict__ Wm,
                          const float* __restrict__ h0, const int* __restrict__ ie,
                          short* __restrict__ embh,
                          short* __restrict__ Wph, short* __restrict__ Wmh,
                          ull* __restrict__ hq, unsigned* __restrict__ flags,
                          int* __restrict__ ctr_del, int* __restrict__ ctr_ins)
{
  int idx = blockIdx.x*256 + threadIdx.x;
  if (idx < 1920000) {                       // embh: 30000*256/4 float4 groups
    float4 v = *(const float4*)(emb + (long)idx*4);
    short4 o; o.x=f2bf(v.x); o.y=f2bf(v.y); o.z=f2bf(v.z); o.w=f2bf(v.w);
    *(short4*)(embh + (long)idx*4) = o;
  } else if (idx < 1985536) {                // Wp: 65536 groups
    int i = idx - 1920000;
    float4 v = *(const float4*)(Wp + (long)i*4);
    short4 o; o.x=f2bf(v.x); o.y=f2bf(v.y); o.z=f2bf(v.z); o.w=f2bf(v.w);
    *(short4*)(Wph + (long)i*4) = o;
  } else if (idx < 2116608) {                // Wm: 131072 groups
    int i = idx - 1985536;
    float4 v = *(const float4*)(Wm + (long)i*4);
    short4 o; o.x=f2bf(v.x); o.y=f2bf(v.y); o.z=f2bf(v.z); o.w=f2bf(v.w);
    *(short4*)(Wmh + (long)i*4) = o;
  } else if (idx < 2124800) {                // h0 -> hq[0]: 8192 qwords, frag order
    int i = idx - 2116608;
    int l = i >> 12, rem = i & 4095;
    int b = rem >> 7, q = rem & 127;        // q = u/4
    const float* src = h0 + b*512 + q*4;
    ull v = ((ull)(unsigned short)f2bf(src[3]) << 48) |
            ((ull)(unsigned short)f2bf(src[2]) << 32) |
            ((ull)(unsigned short)f2bf(src[1]) << 16) |
            ((ull)(unsigned short)f2bf(src[0]));
    int pos = (q >> 3)*256 + (b >> 4)*128 + ((q >> 1) & 3)*32 + (b & 15)*2 + (q & 1);
    hq[(l << 12) + pos] = v;
  } else if (idx < 2124928) {                // zero 128 flag slots
    flags[idx - 2124800] = 0u;
  } else if (idx < 2124960) {                // edit counters (32 serial)
    int b = idx - 2124928;
    int rd = 0, ri = 0;
    for (int t = 0; t < 99; ++t) {
      int a = ie[b*100 + t + 1];
      int incd = (a == 2 || a == 3) ? 1 : 0;
      int inci = (a != 3 && a != 5 && a != 0) ? 1 : 0;
      ctr_del[b*99 + t] = min(rd, 99);
      ctr_ins[b*99 + t] = min(ri, 99);
      rd += incd; ri += inci;
    }
  }
}

// ---------------------------------------------------------------------------
// enc prep: per-batch ench bf16 [100][512] + encTh bf16 [512][128] (zero-pad)
// ---------------------------------------------------------------------------
__global__ __launch_bounds__(256) void enc_prep(const float* __restrict__ enc,
                                                short* __restrict__ ench,
                                                short* __restrict__ encTh)
{
  __shared__ short tile[100][72];
  const int b = blockIdx.x;
  const float* src = enc + (long)b*51200;
  short* de = ench  + (long)b*51200;
  short* dt = encTh + (long)b*65536;
  const int tid = threadIdx.x;
  for (int c = 0; c < 8; ++c) {
    #pragma unroll
    for (int i = 0; i < 25; ++i) {
      int idx = tid + 256*i;
      int k = idx >> 6, j = idx & 63;
      short h = f2bf(src[(long)k*512 + c*64 + j]);
      tile[k][j] = h;
      de[(long)k*512 + c*64 + j] = h;
    }
    __syncthreads();
    #pragma unroll
    for (int i = 0; i < 32; ++i) {
      int idx = tid + 256*i;
      int n = idx >> 7, kk = idx & 127;
      dt[(long)(c*64 + n)*128 + kk] = (kk < 100) ? tile[kk][n] : (short)0;
    }
    __syncthreads();
  }
}

// ---------------------------------------------------------------------------
// bf16 MFMA GEMM body (shared): C[M,N] = act( A @ B^T + bias )
// HQ=1: A row (b*100+t) read from frag-ordered hq (sel via lda)
// ---------------------------------------------------------------------------
template<int GATHER,int CVT_A,int BIAS,int TANH,int OUT_BF16,int HQ>
__device__ __forceinline__ void gemm_mfma_body(
    const void* __restrict__ Av, const int* __restrict__ tok,
    const short* __restrict__ Bh, const float* __restrict__ bias,
    void* __restrict__ Cv, int M, int N, int K, int lda, int ldc,
    int bxk, int byk)
{
  __shared__ short As[128][72];
  __shared__ short Bs[128][72];
  const int bm = bxk * 128;
  const int bn = byk * 128;
  const int tid = threadIdx.x;
  const int w = tid >> 6, l = tid & 63;
  const int wr = (w >> 1) * 64, wc = (w & 1) * 64;
  const int lr = l & 15, kg = l >> 4;

  f32x4 acc[4][4] = {};

  for (int k0 = 0; k0 < K; k0 += 64) {
    #pragma unroll
    for (int q = 0; q < 4; ++q) {
      int ci = tid + 256*q;
      int r = ci >> 3, ch = ci & 7;
      int ar = bm + r; if (ar > M-1) ar = M-1;
      if (GATHER) ar = tok[ar];
      if (CVT_A) {
        const float* ap = ((const float*)Av) + (long)ar*lda + k0 + ch*8;
        float4 v0 = *(const float4*)ap;
        float4 v1 = *(const float4*)(ap + 4);
        short8v s;
        s[0]=f2bf(v0.x); s[1]=f2bf(v0.y); s[2]=f2bf(v0.z); s[3]=f2bf(v0.w);
        s[4]=f2bf(v1.x); s[5]=f2bf(v1.y); s[6]=f2bf(v1.z); s[7]=f2bf(v1.w);
        *(short8v*)&As[r][ch*8] = s;
      } else if (HQ) {
        int bb = ar / 100, tt = ar % 100;
        const short* ap = ((const short*)Av) + hq_elem(tt, lda, bb, k0 + ch*8);
        *(short8v*)&As[r][ch*8] = *(const short8v*)ap;
      } else {
        *(short8v*)&As[r][ch*8] =
            *(const short8v*)(((const short*)Av) + (long)ar*lda + k0 + ch*8);
      }
      int br = bn + r; if (br > N-1) br = N-1;
      *(short8v*)&Bs[r][ch*8] = *(const short8v*)(Bh + (long)br*K + k0 + ch*8);
    }
    __syncthreads();
    #pragma unroll
    for (int ks = 0; ks < 2; ++ks) {
      short8v a[4], b[4];
      #pragma unroll
      for (int m = 0; m < 4; ++m)
        a[m] = *(const short8v*)&As[wr + m*16 + lr][ks*32 + kg*8];
      #pragma unroll
      for (int n = 0; n < 4; ++n)
        b[n] = *(const short8v*)&Bs[wc + n*16 + lr][ks*32 + kg*8];
      #pragma unroll
      for (int m = 0; m < 4; ++m)
        #pragma unroll
        for (int n = 0; n < 4; ++n)
          acc[m][n] = __builtin_amdgcn_mfma_f32_16x16x32_bf16(a[m], b[n], acc[m][n], 0, 0, 0);
    }
    __syncthreads();
  }

  #pragma unroll
  for (int n = 0; n < 4; ++n) {
    int col = bn + wc + n*16 + lr;
    bool cok = (col < N);
    float bv = (BIAS && cok) ? bias[col] : 0.f;
    #pragma unroll
    for (int m = 0; m < 4; ++m) {
      int row0 = bm + wr + m*16 + kg*4;
      #pragma unroll
      for (int r = 0; r < 4; ++r) {
        int row = row0 + r;
        if (cok && row < M) {
          float v = acc[m][n][r] + bv;
          if (TANH) v = tanhc(v);
          if (OUT_BF16) ((short*)Cv)[(long)row*ldc + col] = f2bf(v);
          else          ((float*)Cv)[(long)row*ldc + col] = v;
        }
      }
    }
  }
}

template<int GATHER,int CVT_A,int BIAS,int TANH,int OUT_BF16,int HQ>
__global__ __launch_bounds__(256) void gemm_mfma(
    const void* __restrict__ Av, const int* __restrict__ tok,
    const short* __restrict__ Bh, const float* __restrict__ bias,
    void* __restrict__ Cv, int M, int N, int K, int lda, int ldc)
{
  gemm_mfma_body<GATHER,CVT_A,BIAS,TANH,OUT_BF16,HQ>(
      Av, tok, Bh, bias, Cv, M, N, K, lda, ldc, blockIdx.x, blockIdx.y);
}

// batched variant (blockIdx.z selects batch; element strides sA/sB/sC)
template<int BIAS,int TANH,int OUT_BF16>
__global__ __launch_bounds__(256) void gemm_mfma_bat(
    const short* __restrict__ Ah, const short* __restrict__ Bh,
    const float* __restrict__ bias, void* __restrict__ Cv,
    int M, int N, int K, int lda, int ldc, long sA, long sB, long sC)
{
  const int z = blockIdx.z;
  void* C2 = OUT_BF16 ? (void*)((short*)Cv + (long)z*sC)
                      : (void*)((float*)Cv + (long)z*sC);
  gemm_mfma_body<0,0,BIAS,TANH,OUT_BF16,0>(
      (const void*)(Ah + (long)z*sA), nullptr, Bh + (long)z*sB, bias,
      C2, M, N, K, lda, ldc, blockIdx.x, blockIdx.y);
}

// both Xproj GEMMs in one launch (blockIdx.z selects LSTM); bf16 output
__global__ __launch_bounds__(256) void xproj_mfma(
    const float* __restrict__ emb,
    const int* __restrict__ tokA, const int* __restrict__ tokB,
    const short* __restrict__ WA, const short* __restrict__ WB,
    const float* __restrict__ bA, const float* __restrict__ bB,
    short* __restrict__ outA, short* __restrict__ outB)
{
  const int z = blockIdx.z;
  gemm_mfma_body<1,1,1,0,1,0>(
      emb, z ? tokB : tokA, z ? WB : WA, z ? bB : bA,
      z ? (void*)outB : (void*)outA, 3200, 2048, 256, 256, 2048,
      blockIdx.x, blockIdx.y);
}

// ---------------------------------------------------------------------------
// logits GEMM + per-tile LSE partials; both operands bf16; bf16 logits out.
// ---------------------------------------------------------------------------
__global__ __launch_bounds__(256) void logits_mfma_partial(
    const short* __restrict__ Ah,   // [3168][256] bf16
    const short* __restrict__ Bh,   // [30000][256] bf16
    const float* __restrict__ bias,
    short* __restrict__ Cg,         // [3168][30000] bf16 logits
    float2* __restrict__ partial)   // [3168][NTIL]
{
  __shared__ short As[128][72];
  __shared__ short Bs[128][72];
  __shared__ float2 red[128][2];
  const int bm = blockIdx.x * 128;
  const int bn = blockIdx.y * 128;
  const int tid = threadIdx.x;
  const int w = tid >> 6, l = tid & 63;
  const int wr = (w >> 1) * 64, wc = (w & 1) * 64;
  const int lr = l & 15, kg = l >> 4;

  f32x4 acc[4][4] = {};

  #pragma unroll
  for (int k0 = 0; k0 < 256; k0 += 64) {
    #pragma unroll
    for (int q = 0; q < 4; ++q) {
      int ci = tid + 256*q;
      int r = ci >> 3, ch = ci & 7;
      int ar = bm + r; if (ar > 3167) ar = 3167;
      *(short8v*)&As[r][ch*8] = *(const short8v*)(Ah + (long)ar*256 + k0 + ch*8);
      int br = bn + r; if (br > 29999) br = 29999;
      *(short8v*)&Bs[r][ch*8] = *(const short8v*)(Bh + (long)br*256 + k0 + ch*8);
    }
    __syncthreads();
    #pragma unroll
    for (int ks = 0; ks < 2; ++ks) {
      short8v a[4], b[4];
      #pragma unroll
      for (int m = 0; m < 4; ++m)
        a[m] = *(const short8v*)&As[wr + m*16 + lr][ks*32 + kg*8];
      #pragma unroll
      for (int n = 0; n < 4; ++n)
        b[n] = *(const short8v*)&Bs[wc + n*16 + lr][ks*32 + kg*8];
      #pragma unroll
      for (int m = 0; m < 4; ++m)
        #pragma unroll
        for (int n = 0; n < 4; ++n)
          acc[m][n] = __builtin_amdgcn_mfma_f32_16x16x32_bf16(a[m], b[n], acc[m][n], 0, 0, 0);
    }
    __syncthreads();
  }

  #pragma unroll
  for (int n = 0; n < 4; ++n) {
    int col = bn + wc + n*16 + lr;
    float bv = (col < 30000) ? bias[col] : 0.f;
    #pragma unroll
    for (int m = 0; m < 4; ++m)
      #pragma unroll
      for (int r = 0; r < 4; ++r)
        acc[m][n][r] = (col < 30000) ? acc[m][n][r] + bv : -INFINITY;
  }
  #pragma unroll
  for (int m = 0; m < 4; ++m) {
    #pragma unroll
    for (int r = 0; r < 4; ++r) {
      float a0 = acc[m][0][r], a1 = acc[m][1][r], a2 = acc[m][2][r], a3 = acc[m][3][r];
      float mx = fmaxf(fmaxf(a0, a1), fmaxf(a2, a3));
      #pragma unroll
      for (int off = 1; off < 16; off <<= 1) mx = fmaxf(mx, __shfl_xor(mx, off));
      float se = 0.f;
      if (mx > -INFINITY)
        se = __expf(a0-mx) + __expf(a1-mx) + __expf(a2-mx) + __expf(a3-mx);
      #pragma unroll
      for (int off = 1; off < 16; off <<= 1) se += __shfl_xor(se, off);
      if (lr == 0) red[wr + m*16 + kg*4 + r][w & 1] = make_float2(mx, se);
    }
  }
  #pragma unroll
  for (int n = 0; n < 4; ++n) {
    int col = bn + wc + n*16 + lr;
    if (col < 30000) {
      #pragma unroll
      for (int m = 0; m < 4; ++m) {
        int row0 = bm + wr + m*16 + kg*4;
        #pragma unroll
        for (int r = 0; r < 4; ++r) {
          int row = row0 + r;
          if (row < 3168) Cg[(long)row*30000 + col] = f2bf(acc[m][n][r]);
        }
      }
    }
  }
  __syncthreads();
  if (tid < 128) {
    int row = bm + tid;
    if (row < 3168) {
      float2 A = red[tid][0], B = red[tid][1];
      float M = fmaxf(A.x, B.x);
      float S = 0.f;
      if (M > -INFINITY) S = A.y*__expf(A.x - M) + B.y*__expf(B.x - M);
      partial[(long)row*NTIL + blockIdx.y] = make_float2(M, S);
    }
  }
}

// fused: per-row LSE from partials, then logp = bf16logit - lse
__global__ __launch_bounds__(256) void sub_lse_fused(
    const short* __restrict__ Cg, const float2* __restrict__ partial,
    float* __restrict__ out)
{
  int row = blockIdx.x;
  int tid = threadIdx.x;
  float m = -INFINITY, s = 0.f;
  if (tid < NTIL) {
    float2 p = partial[(long)row*NTIL + tid];
    m = p.x; s = p.y;
  }
  #pragma unroll
  for (int off = 32; off; off >>= 1) {
    float om = __shfl_xor(m, off);
    float os = __shfl_xor(s, off);
    float nm = fmaxf(m, om);
    if (nm > -INFINITY) {
      s = s*__expf(m - nm) + os*__expf(om - nm);
      m = nm;
    }
  }
  __shared__ float sm[4], ss[4], lsh;
  int wv = tid >> 6;
  if ((tid & 63) == 0) { sm[wv] = m; ss[wv] = s; }
  __syncthreads();
  if (tid == 0) {
    float M = sm[0], S = ss[0];
    #pragma unroll
    for (int i = 1; i < 4; ++i) {
      float nm = fmaxf(M, sm[i]);
      S = S*__expf(M - nm) + ss[i]*__expf(sm[i] - nm);
      M = nm;
    }
    lsh = M + __logf(S);
  }
  __syncthreads();
  float lv = lsh;
  const short* src = Cg + (long)row*30000;
  float* dst = out + (long)row*30000;
  for (int i = tid; i < 3750; i += 256) {
    short8v v = *(const short8v*)(src + i*8);
    float4 o0, o1;
    o0.x = bf2f(v[0]) - lv; o0.y = bf2f(v[1]) - lv;
    o0.z = bf2f(v[2]) - lv; o0.w = bf2f(v[3]) - lv;
    o1.x = bf2f(v[4]) - lv; o1.y = bf2f(v[5]) - lv;
    o1.z = bf2f(v[6]) - lv; o1.w = bf2f(v[7]) - lv;
    *(float4*)(dst + i*8)     = o0;
    *(float4*)(dst + i*8 + 4) = o1;
  }
}

// ---------------------------------------------------------------------------
// Persistent LSTM recurrence v7 — frag-ordered hq, NO LDS.
// hq[t] element order = MFMA B-frag order: (b,u) at
//   (u>>5)*1024 + (b>>4)*512 + ((u>>3)&3)*128 + (b&15)*8 + (u&7)
// Consumer wave per-ks load address = lane*16B -> 1KB contiguous per wave;
// 32KB h fits L1, waves 2-4 hit cache. No LDS stage, no stage syncthreads.
// Block flags (R9 protocol): vmcnt(0) -> syncthreads -> tid0 publishes.
// ---------------------------------------------------------------------------
__global__ __launch_bounds__(256, 1) void lstm_persist(
    const short* __restrict__ WhPh_e, const short* __restrict__ WhPh_w,
    const short* __restrict__ Xp_e, const short* __restrict__ Xp_w,
    const float* __restrict__ c0_in,
    ull* __restrict__ hq,        // [101][2][4096] ull, frag-ordered
    float* __restrict__ out_hc,  // he[32][512] then ce[32][512]
    unsigned* __restrict__ flags)// [0..63] block flags; [100] entry fence
{
  const int bx = blockIdx.x;
  const int l = bx >> 5;
  const int ublk = bx & 31;
  const int tid = threadIdx.x;
  const int w = tid >> 6, lane = tid & 63;
  const int uloc = lane >> 4;          // doubles as consumer k-group
  const int bn = lane & 15;
  const int u_global = ublk*16 + w*4 + uloc;
  const int ob = (ublk*16 + w*4) * 4;

  const short* WhPh = l ? WhPh_w : WhPh_e;
  const short* Xp   = l ? Xp_w   : Xp_e;
  const unsigned* myfl = flags + l*32;

  // one-time agent acquire: no cross-replay stale lines in L1/L2
  __hip_atomic_load(&flags[100], __ATOMIC_ACQUIRE, __HIP_MEMORY_SCOPE_AGENT);

  short8v afr[16];
  {
    const short* wp = WhPh + (long)(ob + bn)*512 + uloc*8;
    #pragma unroll
    for (int ks = 0; ks < 16; ++ks)
      afr[ks] = *(const short8v*)(wp + ks*32);
  }
  float c_s0 = c0_in[bn*512 + u_global];
  float c_s1 = c0_in[(bn+16)*512 + u_global];

  // producer store offset (ull): ks*256 + kg*32 + bn*2 + (w&1); +128 for half1
  const int so = ((ublk >> 1) << 8) + (((((ublk & 1) << 1) | (w >> 1))) << 5)
               + (bn << 1) + (w & 1);

  for (int t = 0; t < 100; ++t) {
    // Xp gathers issued early (independent of flags)
    ull xq0 = *(const ull*)(Xp + ((long)(bn*100 + t))*2048 + u_global*4);
    ull xq1 = *(const ull*)(Xp + ((long)((bn+16)*100 + t))*2048 + u_global*4);
    // wait for all 32 producers of this lstm to have published h[t]
    if (t) {
      int ok;
      do {
        unsigned f = (lane < 32)
          ? __hip_atomic_load(&myfl[lane], __ATOMIC_RELAXED, __HIP_MEMORY_SCOPE_AGENT)
          : 0xffffffffu;
        ok = __all((int)(f >= (unsigned)t));
        if (!ok) __builtin_amdgcn_s_sleep(1);
      } while (!ok);
    }
    // direct frag-ordered loads: wave reads 1KB contiguous per ks per half
    const ull* hb = hq + (size_t)t*8192 + (l << 12);
    const ull* r  = hb + (uloc << 5) + (bn << 1);
    f32x4 acc0 = {}, acc1 = {};
    #pragma unroll
    for (int ks = 0; ks < 16; ++ks) {
      short8v b0 = *(const short8v*)(r + ks*256);
      short8v b1 = *(const short8v*)(r + ks*256 + 128);
      acc0 = __builtin_amdgcn_mfma_f32_16x16x32_bf16(afr[ks], b0, acc0, 0, 0, 0);
      acc1 = __builtin_amdgcn_mfma_f32_16x16x32_bf16(afr[ks], b1, acc1, 0, 0, 0);
    }
    float gi = acc0[0] + bf2f((short)(xq0 & 0xffffu));
    float gf = acc0[1] + bf2f((short)((xq0 >> 16) & 0xffffu));
    float gg = acc0[2] + bf2f((short)((xq0 >> 32) & 0xffffu));
    float go = acc0[3] + bf2f((short)((xq0 >> 48) & 0xffffu));
    c_s0 = sigf(gf)*c_s0 + sigf(gi)*tanhc(gg);
    float hv0 = sigf(go)*tanhc(c_s0);
    gi = acc1[0] + bf2f((short)(xq1 & 0xffffu));
    gf = acc1[1] + bf2f((short)((xq1 >> 16) & 0xffffu));
    gg = acc1[2] + bf2f((short)((xq1 >> 32) & 0xffffu));
    go = acc1[3] + bf2f((short)((xq1 >> 48) & 0xffffu));
    c_s1 = sigf(gf)*c_s1 + sigf(gi)*tanhc(gg);
    float hv1 = sigf(go)*tanhc(c_s1);

    short hb0 = f2bf(hv0), hb1 = f2bf(hv1);
    // pack 4 units (uloc 0..3 live in lanes bn, bn+16, bn+32, bn+48)
    unsigned p0 = (unsigned)(unsigned short)hb0;
    unsigned p1 = (unsigned)(unsigned short)hb1;
    unsigned a1 = __shfl_down((int)p0, 16), a2 = __shfl_down((int)p0, 32), a3 = __shfl_down((int)p0, 48);
    unsigned e1 = __shfl_down((int)p1, 16), e2 = __shfl_down((int)p1, 32), e3 = __shfl_down((int)p1, 48);
    if (uloc == 0) {
      ull q0 = ((ull)((a2 & 0xffffu) | (a3 << 16)) << 32) | ((p0 & 0xffffu) | (a1 << 16));
      ull q1 = ((ull)((e2 & 0xffffu) | (e3 << 16)) << 32) | ((p1 & 0xffffu) | (e1 << 16));
      ull* hd = hq + (size_t)(t+1)*8192 + (l << 12);
      __hip_atomic_store(&hd[so],       q0, __ATOMIC_RELAXED, __HIP_MEMORY_SCOPE_AGENT);
      __hip_atomic_store(&hd[so + 128], q1, __ATOMIC_RELAXED, __HIP_MEMORY_SCOPE_AGENT);
    }
    if (t < 99) {
      asm volatile("s_waitcnt vmcnt(0)" ::: "memory");  // own h-stores at L3
      __syncthreads();                                   // whole block drained
      if (tid == 0)
        __hip_atomic_store(&flags[bx], (unsigned)(t+1),
                           __ATOMIC_RELAXED, __HIP_MEMORY_SCOPE_AGENT);
    }
    if (t == 99 && l == 0) {
      out_hc[bn*512 + u_global]              = hv0;
      out_hc[(bn+16)*512 + u_global]         = hv1;
      out_hc[16384 + bn*512 + u_global]      = c_s0;
      out_hc[16384 + (bn+16)*512 + u_global] = c_s1;
    }
  }
}

// softmax over score rows; writes bf16 P zero-padded to 128 cols
__global__ void softmax_rows(const float* __restrict__ P, short* __restrict__ Ph)
{
  int row  = blockIdx.x*4 + (threadIdx.x >> 6);
  int lane = threadIdx.x & 63;
  const float* p = P + (long)row*128;
  short* q = Ph + (long)row*128;
  float x0 = p[lane];
  float x1 = (lane + 64 < 100) ? p[lane+64] : -INFINITY;
  float m = fmaxf(x0, x1);
  #pragma unroll
  for (int off = 32; off; off >>= 1) m = fmaxf(m, __shfl_xor(m, off));
  float e0 = __expf(x0 - m);
  float e1 = (lane + 64 < 100) ? __expf(x1 - m) : 0.f;
  float s = e0 + e1;
  #pragma unroll
  for (int off = 32; off; off >>= 1) s += __shfl_xor(s, off);
  float inv = 1.f / s;
  q[lane]      = f2bf(e0 * inv);
  q[lane + 64] = (lane + 64 < 100) ? f2bf(e1 * inv) : (short)0;
}

// build bf16 feat rows [3168][2048] = [out_e | applied | enc[ctr_del] | out_w[ctr_ins]]
// out_e/out_w segments read frag-ordered hq
__global__ void feat_kernel(const short* __restrict__ hqs, const short* __restrict__ appliedh,
                            const short* __restrict__ ench,
                            const int* __restrict__ ctr_del, const int* __restrict__ ctr_ins,
                            short* __restrict__ feat)
{
  int n = blockIdx.x;                 // 0..3167
  int b = n / 99, t = n % 99;
  int tid = threadIdx.x;
  int seg = tid >> 6;
  int off = (tid & 63) * 8;
  const short* s;
  if (seg == 0)      s = hqs + hq_elem(t, 0, b, off);
  else if (seg == 1) s = appliedh + (long)(b*100 + t)*512 + off;
  else if (seg == 2) s = ench + (long)(b*100 + ctr_del[n])*512 + off;
  else               s = hqs + hq_elem(ctr_ins[n], 1, b, off);
  *(short8v*)(feat + (long)n*2048 + seg*512 + off) = *(const short8v*)s;
}

// ---------------------------------------------------------------------------
extern "C" void kernel_launch(void* const* d_in, const int* in_sizes, int n_in,
                              void* d_out, int out_size, void* d_ws, size_t ws_size,
                              hipStream_t stream)
{
  const int*   input_edits = (const int*)  d_in[0];
  const int*   simp_sent   = (const int*)  d_in[1];
  const float* enc   = (const float*)d_in[3];
  const float* h0    = (const float*)d_in[4];
  const float* c0    = (const float*)d_in[5];
  const float* emb   = (const float*)d_in[6];
  const float* Wi_e  = (const float*)d_in[7];
  const float* Wh_e  = (const float*)d_in[8];
  const float* bi_e  = (const float*)d_in[9];
  const float* bh_e  = (const float*)d_in[10];
  const float* Wi_w  = (const float*)d_in[11];
  const float* Wh_w  = (const float*)d_in[12];
  const float* bi_w  = (const float*)d_in[13];
  const float* bh_w  = (const float*)d_in[14];
  const float* Wp    = (const float*)d_in[15];
  const float* Wm    = (const float*)d_in[16];
  const float* bmv   = (const float*)d_in[17];
  const float* b_out = (const float*)d_in[18];
  float* out = (float*)d_out;

  float* ws = (float*)d_ws;
  size_t off = 0;
  auto alloc = [&](size_t n){ float* p = ws + off; off += (n + 63) & ~(size_t)63; return p; };

  short* WiPh_e   = (short*)alloc(262144);   // 2048*256 bf16
  short* WiPh_w   = (short*)alloc(262144);
  float* biasP_e  = alloc(2048);
  float* biasP_w  = alloc(2048);
  short* WhPh_e   = (short*)alloc(524288);   // 2048*512 bf16
  short* WhPh_w   = (short*)alloc(524288);
  short* Xp_e     = (short*)alloc(3276800);  // 3200*2048 bf16
  short* Xp_w     = (short*)alloc(3276800);
  ull*   hq       = (ull*)alloc(101*8192*2); // 101 step buffers x 64KB
  unsigned* flags = (unsigned*)alloc(128);   // block flags + fence slot
  float* Pbuf     = alloc(409600);           // 3200*128 f32 scores
  short* Pbh      = (short*)alloc(204800);   // 3200*128 bf16 softmax
  int*   ctr_del  = (int*)alloc(3168);
  int*   ctr_ins  = (int*)alloc(3168);
  short* Wph      = (short*)alloc(131072);   // 512*512 bf16
  short* Wmh      = (short*)alloc(262144);   // 256*2048 bf16
  short* keyh     = (short*)alloc(819200);   // 3200*512 bf16
  short* appliedh = (short*)alloc(819200);   // 3200*512 bf16
  short* ench     = (short*)alloc(819200);   // 32*100*512 bf16
  short* encTh    = (short*)alloc(1048576);  // 32*512*128 bf16
  short* embh     = (short*)alloc(3840000);  // 30000*256 bf16
  short* logith   = (short*)alloc(47520000); // 3168*30000 bf16 logits
  float2* partial = (float2*)alloc(3168*NTIL*2);
  // overlays (lifetimes disjoint, stream-ordered):
  short* feath    = (short*)Xp_e;            // 3168*2048 bf16, after recurrence
  short* hmlph    = (short*)Xp_w;            // 3168*256 bf16, after MLP

  // 1) weight prep + misc prep (embh, convs, h0->hq[0], flags, counters) + enc
  prep_permute<<<dim3(4096,2), 256, 0, stream>>>(
      Wi_e, Wh_e, bi_e, bh_e, Wi_w, Wh_w, bi_w, bh_w,
      WiPh_e, WhPh_e, biasP_e, WiPh_w, WhPh_w, biasP_w);
  misc_prep<<<8301, 256, 0, stream>>>(emb, Wp, Wm, h0, input_edits,
                                      embh, Wph, Wmh, hq, flags, ctr_del, ctr_ins);
  enc_prep<<<32, 256, 0, stream>>>(enc, ench, encTh);

  // 2) Xproj both LSTMs, one launch, bf16 out
  xproj_mfma<<<dim3(25,16,2), 256, 0, stream>>>(
      emb, input_edits, simp_sent, WiPh_e, WiPh_w, biasP_e, biasP_w, Xp_e, Xp_w);

  // 3) recurrence: persistent, frag-ordered hq, no LDS
  lstm_persist<<<LSTM_BLOCKS, 256, 0, stream>>>(
      WhPh_e, WhPh_w, Xp_e, Xp_w, c0, hq, out + 95040000L, flags);

  // 4) key = hq(out_e) @ Wp^T  (MFMA, HQ addressing, bf16 out)
  gemm_mfma<0,0,0,0,1,1><<<dim3(25,4), 256, 0, stream>>>(
      hq, nullptr, Wph, nullptr, keyh, 3200, 512, 512, 0 /*sel=e*/, 512);

  // 5) attention (all MFMA): scores -> softmax(bf16) -> applied(bf16)
  gemm_mfma_bat<0,0,0><<<dim3(1,1,32), 256, 0, stream>>>(
      keyh, ench, nullptr, Pbuf, 100, 100, 512, 512, 128,
      51200, 51200, 12800);
  softmax_rows<<<800, 256, 0, stream>>>(Pbuf, Pbh);
  gemm_mfma_bat<0,0,1><<<dim3(1,4,32), 256, 0, stream>>>(
      Pbh, encTh, nullptr, appliedh, 100, 512, 128, 128, 512,
      12800, 65536, 51200);

  // 6) feat (frag-ordered hq reads) + MLP (MFMA, tanh, bf16 out)
  feat_kernel<<<3168, 256, 0, stream>>>((const short*)hq, appliedh, ench,
                                        ctr_del, ctr_ins, feath);
  gemm_mfma<0,0,1,1,1,0><<<dim3(25,2), 256, 0, stream>>>(
      feath, nullptr, Wmh, bmv, hmlph, 3168, 256, 2048, 2048, 256);

  // 7) logits (MFMA, all-bf16, LSE partials) + fused log-softmax subtract
  logits_mfma_partial<<<dim3(25, NTIL), 256, 0, stream>>>(
      hmlph, embh, b_out, logith, partial);
  sub_lse_fused<<<3168, 256, 0, stream>>>(logith, partial, out);
}

// Round 14
// 1033.327 us; speedup vs baseline: 1.1898x; 1.1898x over previous
//
#include <hip/hip_runtime.h>
#include <math.h>

// Sizes (fixed): B=32, T=100, S=100, H=512, E=256, V=30000, 4H=2048, M_log=3168

typedef __attribute__((ext_vector_type(8))) short short8v;  // 8 bf16 (4 VGPRs)
typedef __attribute__((ext_vector_type(4))) float f32x4;
typedef unsigned long long ull;

#define LSTM_BLOCKS 64
#define NTIL 235

__device__ __forceinline__ float sigf(float x){ return 1.0f/(1.0f + __expf(-x)); }
__device__ __forceinline__ float tanhc(float x){
  x = fminf(fmaxf(x, -15.f), 15.f);
  float e = __expf(2.f*x);
  return (e-1.f)/(e+1.f);
}
__device__ __forceinline__ short f2bf(float f){
  unsigned u = __float_as_uint(f);
  u = (u + 0x7fffu + ((u >> 16) & 1u)) >> 16;
  return (short)u;
}
__device__ __forceinline__ float bf2f(short s){
  return __uint_as_float(((unsigned)(unsigned short)s) << 16);
}

// ---------------------------------------------------------------------------
// prep_all: one launch for ALL prep work, dispatched by blockIdx range.
//  [0,8192)      gate-permuted weights, both LSTMs (z = blk>>12)
//  [8192,16493)  misc: emb->bf16, Wp, Wm, h0->hq[0], flags, counters
//  [16493,16525) enc prep: ench + encTh (padded transpose)
// ---------------------------------------------------------------------------
__global__ __launch_bounds__(256) void prep_all(
    const float* __restrict__ Wi_e, const float* __restrict__ Wh_e,
    const float* __restrict__ bi_e, const float* __restrict__ bh_e,
    const float* __restrict__ Wi_w, const float* __restrict__ Wh_w,
    const float* __restrict__ bi_w, const float* __restrict__ bh_w,
    const float* __restrict__ emb,  const float* __restrict__ Wp,
    const float* __restrict__ Wm,   const float* __restrict__ h0,
    const int* __restrict__ ie,     const float* __restrict__ enc,
    short* __restrict__ WiPh_e, short* __restrict__ WhPh_e, float* __restrict__ biasP_e,
    short* __restrict__ WiPh_w, short* __restrict__ WhPh_w, float* __restrict__ biasP_w,
    short* __restrict__ embh, short* __restrict__ Wph, short* __restrict__ Wmh,
    ull* __restrict__ hq, unsigned* __restrict__ flags,
    int* __restrict__ ctr_del, int* __restrict__ ctr_ins,
    short* __restrict__ ench, short* __restrict__ encTh)
{
  const int blk = blockIdx.x;
  const int tid = threadIdx.x;

  if (blk < 8192) {                     // ---- weight permute (both LSTMs)
    const int z  = blk >> 12;
    const int bx = blk & 4095;
    const float* Wi = z ? Wi_w : Wi_e;
    const float* Wh = z ? Wh_w : Wh_e;
    const float* bi = z ? bi_w : bi_e;
    const float* bh = z ? bh_w : bh_e;
    short* WiPh = z ? WiPh_w : WiPh_e;
    short* WhPh = z ? WhPh_w : WhPh_e;
    float* biasP = z ? biasP_w : biasP_e;
    int idx = bx*256 + tid;             // 0 .. 1048575
    {
      int op = idx >> 9, k = idx & 511;
      int u = op >> 2, g = op & 3;
      WhPh[idx] = f2bf(Wh[(g*512+u)*512 + k]);
    }
    if (idx < 2048*256) {
      int op = idx >> 8, e = idx & 255;
      int u = op >> 2, g = op & 3;
      WiPh[idx] = f2bf(Wi[(g*512+u)*256 + e]);
    }
    if (idx < 2048) {
      int u = idx >> 2, g = idx & 3;
      biasP[idx] = bi[g*512+u] + bh[g*512+u];
    }
  } else if (blk < 16493) {             // ---- misc
    int idx = (blk - 8192)*256 + tid;
    if (idx < 1920000) {                       // embh
      float4 v = *(const float4*)(emb + (long)idx*4);
      short4 o; o.x=f2bf(v.x); o.y=f2bf(v.y); o.z=f2bf(v.z); o.w=f2bf(v.w);
      *(short4*)(embh + (long)idx*4) = o;
    } else if (idx < 1985536) {                // Wp
      int i = idx - 1920000;
      float4 v = *(const float4*)(Wp + (long)i*4);
      short4 o; o.x=f2bf(v.x); o.y=f2bf(v.y); o.z=f2bf(v.z); o.w=f2bf(v.w);
      *(short4*)(Wph + (long)i*4) = o;
    } else if (idx < 2116608) {                // Wm
      int i = idx - 1985536;
      float4 v = *(const float4*)(Wm + (long)i*4);
      short4 o; o.x=f2bf(v.x); o.y=f2bf(v.y); o.z=f2bf(v.z); o.w=f2bf(v.w);
      *(short4*)(Wmh + (long)i*4) = o;
    } else if (idx < 2124800) {                // h0 -> hq[0]: 8192 qwords
      int i = idx - 2116608;                   // (l<<12)+(b<<7)+q
      int b = (i >> 7) & 31, q = i & 127;
      const float* src = h0 + b*512 + q*4;
      ull v = ((ull)(unsigned short)f2bf(src[3]) << 48) |
              ((ull)(unsigned short)f2bf(src[2]) << 32) |
              ((ull)(unsigned short)f2bf(src[1]) << 16) |
              ((ull)(unsigned short)f2bf(src[0]));
      hq[i] = v;
    } else if (idx < 2124928) {                // zero flag slots
      flags[idx - 2124800] = 0u;
    } else if (idx < 2124960) {                // edit counters
      int b = idx - 2124928;
      int rd = 0, ri = 0;
      for (int t = 0; t < 99; ++t) {
        int a = ie[b*100 + t + 1];
        int incd = (a == 2 || a == 3) ? 1 : 0;
        int inci = (a != 3 && a != 5 && a != 0) ? 1 : 0;
        ctr_del[b*99 + t] = min(rd, 99);
        ctr_ins[b*99 + t] = min(ri, 99);
        rd += incd; ri += inci;
      }
    }
  } else {                              // ---- enc prep (32 blocks)
    __shared__ short tile[100][72];
    const int b = blk - 16493;
    const float* src = enc + (long)b*51200;
    short* de = ench  + (long)b*51200;
    short* dt = encTh + (long)b*65536;
    for (int c = 0; c < 8; ++c) {
      #pragma unroll
      for (int i = 0; i < 25; ++i) {
        int idx = tid + 256*i;
        int k = idx >> 6, j = idx & 63;
        short h = f2bf(src[(long)k*512 + c*64 + j]);
        tile[k][j] = h;
        de[(long)k*512 + c*64 + j] = h;
      }
      __syncthreads();
      #pragma unroll
      for (int i = 0; i < 32; ++i) {
        int idx = tid + 256*i;
        int n = idx >> 7, kk = idx & 127;
        dt[(long)(c*64 + n)*128 + kk] = (kk < 100) ? tile[kk][n] : (short)0;
      }
      __syncthreads();
    }
  }
}

// ---------------------------------------------------------------------------
// bf16 MFMA GEMM body (shared): C[M,N] = act( A @ B^T + bias )
// HQ=1: A row (b*100+t) read from hq linear layout at
//       (short*)Av + (t+1)*32768 + sel*16384 + b*512   (sel via lda)
// ---------------------------------------------------------------------------
template<int GATHER,int CVT_A,int BIAS,int TANH,int OUT_BF16,int HQ>
__device__ __forceinline__ void gemm_mfma_body(
    const void* __restrict__ Av, const int* __restrict__ tok,
    const short* __restrict__ Bh, const float* __restrict__ bias,
    void* __restrict__ Cv, int M, int N, int K, int lda, int ldc,
    int bxk, int byk)
{
  __shared__ short As[128][72];
  __shared__ short Bs[128][72];
  const int bm = bxk * 128;
  const int bn = byk * 128;
  const int tid = threadIdx.x;
  const int w = tid >> 6, l = tid & 63;
  const int wr = (w >> 1) * 64, wc = (w & 1) * 64;
  const int lr = l & 15, kg = l >> 4;

  f32x4 acc[4][4] = {};

  for (int k0 = 0; k0 < K; k0 += 64) {
    #pragma unroll
    for (int q = 0; q < 4; ++q) {
      int ci = tid + 256*q;
      int r = ci >> 3, ch = ci & 7;
      int ar = bm + r; if (ar > M-1) ar = M-1;
      if (GATHER) ar = tok[ar];
      if (CVT_A) {
        const float* ap = ((const float*)Av) + (long)ar*lda + k0 + ch*8;
        float4 v0 = *(const float4*)ap;
        float4 v1 = *(const float4*)(ap + 4);
        short8v s;
        s[0]=f2bf(v0.x); s[1]=f2bf(v0.y); s[2]=f2bf(v0.z); s[3]=f2bf(v0.w);
        s[4]=f2bf(v1.x); s[5]=f2bf(v1.y); s[6]=f2bf(v1.z); s[7]=f2bf(v1.w);
        *(short8v*)&As[r][ch*8] = s;
      } else if (HQ) {
        int bb = ar / 100, tt = ar % 100;
        const short* ap = ((const short*)Av) + (long)(tt+1)*32768
                        + (long)lda*16384 + bb*512 + k0 + ch*8;
        *(short8v*)&As[r][ch*8] = *(const short8v*)ap;
      } else {
        *(short8v*)&As[r][ch*8] =
            *(const short8v*)(((const short*)Av) + (long)ar*lda + k0 + ch*8);
      }
      int br = bn + r; if (br > N-1) br = N-1;
      *(short8v*)&Bs[r][ch*8] = *(const short8v*)(Bh + (long)br*K + k0 + ch*8);
    }
    __syncthreads();
    #pragma unroll
    for (int ks = 0; ks < 2; ++ks) {
      short8v a[4], b[4];
      #pragma unroll
      for (int m = 0; m < 4; ++m)
        a[m] = *(const short8v*)&As[wr + m*16 + lr][ks*32 + kg*8];
      #pragma unroll
      for (int n = 0; n < 4; ++n)
        b[n] = *(const short8v*)&Bs[wc + n*16 + lr][ks*32 + kg*8];
      #pragma unroll
      for (int m = 0; m < 4; ++m)
        #pragma unroll
        for (int n = 0; n < 4; ++n)
          acc[m][n] = __builtin_amdgcn_mfma_f32_16x16x32_bf16(a[m], b[n], acc[m][n], 0, 0, 0);
    }
    __syncthreads();
  }

  #pragma unroll
  for (int n = 0; n < 4; ++n) {
    int col = bn + wc + n*16 + lr;
    bool cok = (col < N);
    float bv = (BIAS && cok) ? bias[col] : 0.f;
    #pragma unroll
    for (int m = 0; m < 4; ++m) {
      int row0 = bm + wr + m*16 + kg*4;
      #pragma unroll
      for (int r = 0; r < 4; ++r) {
        int row = row0 + r;
        if (cok && row < M) {
          float v = acc[m][n][r] + bv;
          if (TANH) v = tanhc(v);
          if (OUT_BF16) ((short*)Cv)[(long)row*ldc + col] = f2bf(v);
          else          ((float*)Cv)[(long)row*ldc + col] = v;
        }
      }
    }
  }
}

template<int GATHER,int CVT_A,int BIAS,int TANH,int OUT_BF16,int HQ>
__global__ __launch_bounds__(256) void gemm_mfma(
    const void* __restrict__ Av, const int* __restrict__ tok,
    const short* __restrict__ Bh, const float* __restrict__ bias,
    void* __restrict__ Cv, int M, int N, int K, int lda, int ldc)
{
  gemm_mfma_body<GATHER,CVT_A,BIAS,TANH,OUT_BF16,HQ>(
      Av, tok, Bh, bias, Cv, M, N, K, lda, ldc, blockIdx.x, blockIdx.y);
}

// batched variant (blockIdx.z selects batch; element strides sA/sB/sC)
template<int BIAS,int TANH,int OUT_BF16>
__global__ __launch_bounds__(256) void gemm_mfma_bat(
    const short* __restrict__ Ah, const short* __restrict__ Bh,
    const float* __restrict__ bias, void* __restrict__ Cv,
    int M, int N, int K, int lda, int ldc, long sA, long sB, long sC)
{
  const int z = blockIdx.z;
  void* C2 = OUT_BF16 ? (void*)((short*)Cv + (long)z*sC)
                      : (void*)((float*)Cv + (long)z*sC);
  gemm_mfma_body<0,0,BIAS,TANH,OUT_BF16,0>(
      (const void*)(Ah + (long)z*sA), nullptr, Bh + (long)z*sB, bias,
      C2, M, N, K, lda, ldc, blockIdx.x, blockIdx.y);
}

// both Xproj GEMMs in one launch (blockIdx.z selects LSTM); bf16 output
__global__ __launch_bounds__(256) void xproj_mfma(
    const float* __restrict__ emb,
    const int* __restrict__ tokA, const int* __restrict__ tokB,
    const short* __restrict__ WA, const short* __restrict__ WB,
    const float* __restrict__ bA, const float* __restrict__ bB,
    short* __restrict__ outA, short* __restrict__ outB)
{
  const int z = blockIdx.z;
  gemm_mfma_body<1,1,1,0,1,0>(
      emb, z ? tokB : tokA, z ? WB : WA, z ? bB : bA,
      z ? (void*)outB : (void*)outA, 3200, 2048, 256, 256, 2048,
      blockIdx.x, blockIdx.y);
}

// ---------------------------------------------------------------------------
// logits GEMM + per-tile LSE partials; both operands bf16; bf16 logits out.
// ---------------------------------------------------------------------------
__global__ __launch_bounds__(256) void logits_mfma_partial(
    const short* __restrict__ Ah,   // [3168][256] bf16
    const short* __restrict__ Bh,   // [30000][256] bf16
    const float* __restrict__ bias,
    short* __restrict__ Cg,         // [3168][30000] bf16 logits
    float2* __restrict__ partial)   // [3168][NTIL]
{
  __shared__ short As[128][72];
  __shared__ short Bs[128][72];
  __shared__ float2 red[128][2];
  const int bm = blockIdx.x * 128;
  const int bn = blockIdx.y * 128;
  const int tid = threadIdx.x;
  const int w = tid >> 6, l = tid & 63;
  const int wr = (w >> 1) * 64, wc = (w & 1) * 64;
  const int lr = l & 15, kg = l >> 4;

  f32x4 acc[4][4] = {};

  #pragma unroll
  for (int k0 = 0; k0 < 256; k0 += 64) {
    #pragma unroll
    for (int q = 0; q < 4; ++q) {
      int ci = tid + 256*q;
      int r = ci >> 3, ch = ci & 7;
      int ar = bm + r; if (ar > 3167) ar = 3167;
      *(short8v*)&As[r][ch*8] = *(const short8v*)(Ah + (long)ar*256 + k0 + ch*8);
      int br = bn + r; if (br > 29999) br = 29999;
      *(short8v*)&Bs[r][ch*8] = *(const short8v*)(Bh + (long)br*256 + k0 + ch*8);
    }
    __syncthreads();
    #pragma unroll
    for (int ks = 0; ks < 2; ++ks) {
      short8v a[4], b[4];
      #pragma unroll
      for (int m = 0; m < 4; ++m)
        a[m] = *(const short8v*)&As[wr + m*16 + lr][ks*32 + kg*8];
      #pragma unroll
      for (int n = 0; n < 4; ++n)
        b[n] = *(const short8v*)&Bs[wc + n*16 + lr][ks*32 + kg*8];
      #pragma unroll
      for (int m = 0; m < 4; ++m)
        #pragma unroll
        for (int n = 0; n < 4; ++n)
          acc[m][n] = __builtin_amdgcn_mfma_f32_16x16x32_bf16(a[m], b[n], acc[m][n], 0, 0, 0);
    }
    __syncthreads();
  }

  #pragma unroll
  for (int n = 0; n < 4; ++n) {
    int col = bn + wc + n*16 + lr;
    float bv = (col < 30000) ? bias[col] : 0.f;
    #pragma unroll
    for (int m = 0; m < 4; ++m)
      #pragma unroll
      for (int r = 0; r < 4; ++r)
        acc[m][n][r] = (col < 30000) ? acc[m][n][r] + bv : -INFINITY;
  }
  #pragma unroll
  for (int m = 0; m < 4; ++m) {
    #pragma unroll
    for (int r = 0; r < 4; ++r) {
      float a0 = acc[m][0][r], a1 = acc[m][1][r], a2 = acc[m][2][r], a3 = acc[m][3][r];
      float mx = fmaxf(fmaxf(a0, a1), fmaxf(a2, a3));
      #pragma unroll
      for (int off = 1; off < 16; off <<= 1) mx = fmaxf(mx, __shfl_xor(mx, off));
      float se = 0.f;
      if (mx > -INFINITY)
        se = __expf(a0-mx) + __expf(a1-mx) + __expf(a2-mx) + __expf(a3-mx);
      #pragma unroll
      for (int off = 1; off < 16; off <<= 1) se += __shfl_xor(se, off);
      if (lr == 0) red[wr + m*16 + kg*4 + r][w & 1] = make_float2(mx, se);
    }
  }
  #pragma unroll
  for (int n = 0; n < 4; ++n) {
    int col = bn + wc + n*16 + lr;
    if (col < 30000) {
      #pragma unroll
      for (int m = 0; m < 4; ++m) {
        int row0 = bm + wr + m*16 + kg*4;
        #pragma unroll
        for (int r = 0; r < 4; ++r) {
          int row = row0 + r;
          if (row < 3168) Cg[(long)row*30000 + col] = f2bf(acc[m][n][r]);
        }
      }
    }
  }
  __syncthreads();
  if (tid < 128) {
    int row = bm + tid;
    if (row < 3168) {
      float2 A = red[tid][0], B = red[tid][1];
      float M = fmaxf(A.x, B.x);
      float S = 0.f;
      if (M > -INFINITY) S = A.y*__expf(A.x - M) + B.y*__expf(B.x - M);
      partial[(long)row*NTIL + blockIdx.y] = make_float2(M, S);
    }
  }
}

// fused: per-row LSE from partials, then logp = bf16logit - lse
__global__ __launch_bounds__(256) void sub_lse_fused(
    const short* __restrict__ Cg, const float2* __restrict__ partial,
    float* __restrict__ out)
{
  int row = blockIdx.x;
  int tid = threadIdx.x;
  float m = -INFINITY, s = 0.f;
  if (tid < NTIL) {
    float2 p = partial[(long)row*NTIL + tid];
    m = p.x; s = p.y;
  }
  #pragma unroll
  for (int off = 32; off; off >>= 1) {
    float om = __shfl_xor(m, off);
    float os = __shfl_xor(s, off);
    float nm = fmaxf(m, om);
    if (nm > -INFINITY) {
      s = s*__expf(m - nm) + os*__expf(om - nm);
      m = nm;
    }
  }
  __shared__ float sm[4], ss[4], lsh;
  int wv = tid >> 6;
  if ((tid & 63) == 0) { sm[wv] = m; ss[wv] = s; }
  __syncthreads();
  if (tid == 0) {
    float M = sm[0], S = ss[0];
    #pragma unroll
    for (int i = 1; i < 4; ++i) {
      float nm = fmaxf(M, sm[i]);
      S = S*__expf(M - nm) + ss[i]*__expf(sm[i] - nm);
      M = nm;
    }
    lsh = M + __logf(S);
  }
  __syncthreads();
  float lv = lsh;
  const short* src = Cg + (long)row*30000;
  float* dst = out + (long)row*30000;
  for (int i = tid; i < 3750; i += 256) {
    short8v v = *(const short8v*)(src + i*8);
    float4 o0, o1;
    o0.x = bf2f(v[0]) - lv; o0.y = bf2f(v[1]) - lv;
    o0.z = bf2f(v[2]) - lv; o0.w = bf2f(v[3]) - lv;
    o1.x = bf2f(v[4]) - lv; o1.y = bf2f(v[5]) - lv;
    o1.z = bf2f(v[6]) - lv; o1.w = bf2f(v[7]) - lv;
    *(float4*)(dst + i*8)     = o0;
    *(float4*)(dst + i*8 + 4) = o1;
  }
}

// ---------------------------------------------------------------------------
// Persistent LSTM recurrence (R12 structure — known-good 377us).
// LDS-staged coalesced h loads; block producer flags (packed, 2 lines/LSTM);
// hq[t+1] is both next-state and sequence output (linear [l][b][u] layout).
// ---------------------------------------------------------------------------
__global__ __launch_bounds__(256, 1) void lstm_persist(
    const short* __restrict__ WhPh_e, const short* __restrict__ WhPh_w,
    const short* __restrict__ Xp_e, const short* __restrict__ Xp_w,
    const float* __restrict__ c0_in,
    ull* __restrict__ hq,        // [101][2][32][128] qwords
    float* __restrict__ out_hc,  // he[32][512] then ce[32][512]
    unsigned* __restrict__ flags)// [0..63] block flags; [100] entry fence
{
  const int bx = blockIdx.x;
  const int l = bx >> 5;
  const int ublk = bx & 31;
  const int tid = threadIdx.x;
  const int w = tid >> 6, lane = tid & 63;
  const int uloc = lane >> 4;
  const int bn = lane & 15;
  const int u_global = ublk*16 + w*4 + uloc;
  const int ob = (ublk*16 + w*4) * 4;
  const int qcol = ublk*4 + w;

  const short* WhPh = l ? WhPh_w : WhPh_e;
  const short* Xp   = l ? Xp_w   : Xp_e;
  const unsigned* myfl = flags + l*32;

  __shared__ short hT[32][520];

  // one-time agent acquire: no cross-replay stale lines in L1/L2
  __hip_atomic_load(&flags[100], __ATOMIC_ACQUIRE, __HIP_MEMORY_SCOPE_AGENT);

  short8v afr[16];
  {
    const short* wp = WhPh + (long)(ob + bn)*512 + uloc*8;
    #pragma unroll
    for (int ks = 0; ks < 16; ++ks)
      afr[ks] = *(const short8v*)(wp + ks*32);
  }
  float c_s0 = c0_in[bn*512 + u_global];
  float c_s1 = c0_in[(bn+16)*512 + u_global];

  for (int t = 0; t < 100; ++t) {
    // Xp gathers issued early (independent of flags)
    ull xq0 = *(const ull*)(Xp + ((long)(bn*100 + t))*2048 + u_global*4);
    ull xq1 = *(const ull*)(Xp + ((long)((bn+16)*100 + t))*2048 + u_global*4);
    // wait for all 32 producers of this lstm to have published h[t]
    if (t) {
      int ok;
      do {
        unsigned f = (lane < 32)
          ? __hip_atomic_load(&myfl[lane], __ATOMIC_RELAXED, __HIP_MEMORY_SCOPE_AGENT)
          : 0xffffffffu;
        ok = __all((int)(f >= (unsigned)t));
        if (!ok) __builtin_amdgcn_s_sleep(1);
      } while (!ok);
    }
    // stage h: coalesced loads of this step's single-use buffer -> LDS
    {
      const ull* hsrc = hq + (size_t)t*8192 + (l << 12);
      #pragma unroll
      for (int i = 0; i < 16; ++i) {
        int idx = tid + 256*i;
        int b = idx >> 7, q = idx & 127;
        *(ull*)&hT[b][q*4] = hsrc[idx];
      }
    }
    __syncthreads();
    f32x4 acc0 = {}, acc1 = {};
    #pragma unroll
    for (int ks = 0; ks < 16; ++ks) {
      short8v b0 = *(const short8v*)&hT[bn][ks*32 + uloc*8];
      short8v b1 = *(const short8v*)&hT[bn+16][ks*32 + uloc*8];
      acc0 = __builtin_amdgcn_mfma_f32_16x16x32_bf16(afr[ks], b0, acc0, 0, 0, 0);
      acc1 = __builtin_amdgcn_mfma_f32_16x16x32_bf16(afr[ks], b1, acc1, 0, 0, 0);
    }
    float gi = acc0[0] + bf2f((short)(xq0 & 0xffffu));
    float gf = acc0[1] + bf2f((short)((xq0 >> 16) & 0xffffu));
    float gg = acc0[2] + bf2f((short)((xq0 >> 32) & 0xffffu));
    float go = acc0[3] + bf2f((short)((xq0 >> 48) & 0xffffu));
    c_s0 = sigf(gf)*c_s0 + sigf(gi)*tanhc(gg);
    float hv0 = sigf(go)*tanhc(c_s0);
    gi = acc1[0] + bf2f((short)(xq1 & 0xffffu));
    gf = acc1[1] + bf2f((short)((xq1 >> 16) & 0xffffu));
    gg = acc1[2] + bf2f((short)((xq1 >> 32) & 0xffffu));
    go = acc1[3] + bf2f((short)((xq1 >> 48) & 0xffffu));
    c_s1 = sigf(gf)*c_s1 + sigf(gi)*tanhc(gg);
    float hv1 = sigf(go)*tanhc(c_s1);

    short hb0 = f2bf(hv0), hb1 = f2bf(hv1);
    unsigned p0 = (unsigned)(unsigned short)hb0;
    unsigned p1 = (unsigned)(unsigned short)hb1;
    unsigned a1 = __shfl_down((int)p0, 16), a2 = __shfl_down((int)p0, 32), a3 = __shfl_down((int)p0, 48);
    unsigned e1 = __shfl_down((int)p1, 16), e2 = __shfl_down((int)p1, 32), e3 = __shfl_down((int)p1, 48);
    if (uloc == 0) {
      ull q0 = ((ull)((a2 & 0xffffu) | (a3 << 16)) << 32) | ((p0 & 0xffffu) | (a1 << 16));
      ull q1 = ((ull)((e2 & 0xffffu) | (e3 << 16)) << 32) | ((p1 & 0xffffu) | (e1 << 16));
      ull* hd = hq + (size_t)(t+1)*8192 + (l << 12);
      __hip_atomic_store(&hd[(bn << 7) + qcol],      q0, __ATOMIC_RELAXED, __HIP_MEMORY_SCOPE_AGENT);
      __hip_atomic_store(&hd[((bn+16) << 7) + qcol], q1, __ATOMIC_RELAXED, __HIP_MEMORY_SCOPE_AGENT);
    }
    if (t < 99) {
      asm volatile("s_waitcnt vmcnt(0)" ::: "memory");  // own h-stores at L3
      __syncthreads();                                   // whole block drained
      if (tid == 0)
        __hip_atomic_store(&flags[bx], (unsigned)(t+1),
                           __ATOMIC_RELAXED, __HIP_MEMORY_SCOPE_AGENT);
    }
    if (t == 99 && l == 0) {
      out_hc[bn*512 + u_global]              = hv0;
      out_hc[(bn+16)*512 + u_global]         = hv1;
      out_hc[16384 + bn*512 + u_global]      = c_s0;
      out_hc[16384 + (bn+16)*512 + u_global] = c_s1;
    }
  }
}

// softmax over score rows; writes bf16 P zero-padded to 128 cols
__global__ void softmax_rows(const float* __restrict__ P, short* __restrict__ Ph)
{
  int row  = blockIdx.x*4 + (threadIdx.x >> 6);
  int lane = threadIdx.x & 63;
  const float* p = P + (long)row*128;
  short* q = Ph + (long)row*128;
  float x0 = p[lane];
  float x1 = (lane + 64 < 100) ? p[lane+64] : -INFINITY;
  float m = fmaxf(x0, x1);
  #pragma unroll
  for (int off = 32; off; off >>= 1) m = fmaxf(m, __shfl_xor(m, off));
  float e0 = __expf(x0 - m);
  float e1 = (lane + 64 < 100) ? __expf(x1 - m) : 0.f;
  float s = e0 + e1;
  #pragma unroll
  for (int off = 32; off; off >>= 1) s += __shfl_xor(s, off);
  float inv = 1.f / s;
  q[lane]      = f2bf(e0 * inv);
  q[lane + 64] = (lane + 64 < 100) ? f2bf(e1 * inv) : (short)0;
}

// build bf16 feat rows [3168][2048] = [out_e | applied | enc[ctr_del] | out_w[ctr_ins]]
// out_e/out_w segments read straight from hq: (t+1)*32768 + l*16384 + b*512
__global__ void feat_kernel(const short* __restrict__ hqs, const short* __restrict__ appliedh,
                            const short* __restrict__ ench,
                            const int* __restrict__ ctr_del, const int* __restrict__ ctr_ins,
                            short* __restrict__ feat)
{
  int n = blockIdx.x;                 // 0..3167
  int b = n / 99, t = n % 99;
  int tid = threadIdx.x;
  int seg = tid >> 6;
  int off = (tid & 63) * 8;
  const short* s = (seg == 0) ? hqs + (long)(t+1)*32768 + b*512
                 : (seg == 1) ? appliedh + (long)(b*100 + t)*512
                 : (seg == 2) ? ench + (long)(b*100 + ctr_del[n])*512
                              : hqs + (long)(ctr_ins[n]+1)*32768 + 16384 + b*512;
  *(short8v*)(feat + (long)n*2048 + seg*512 + off) = *(const short8v*)(s + off);
}

// ---------------------------------------------------------------------------
extern "C" void kernel_launch(void* const* d_in, const int* in_sizes, int n_in,
                              void* d_out, int out_size, void* d_ws, size_t ws_size,
                              hipStream_t stream)
{
  const int*   input_edits = (const int*)  d_in[0];
  const int*   simp_sent   = (const int*)  d_in[1];
  const float* enc   = (const float*)d_in[3];
  const float* h0    = (const float*)d_in[4];
  const float* c0    = (const float*)d_in[5];
  const float* emb   = (const float*)d_in[6];
  const float* Wi_e  = (const float*)d_in[7];
  const float* Wh_e  = (const float*)d_in[8];
  const float* bi_e  = (const float*)d_in[9];
  const float* bh_e  = (const float*)d_in[10];
  const float* Wi_w  = (const float*)d_in[11];
  const float* Wh_w  = (const float*)d_in[12];
  const float* bi_w  = (const float*)d_in[13];
  const float* bh_w  = (const float*)d_in[14];
  const float* Wp    = (const float*)d_in[15];
  const float* Wm    = (const float*)d_in[16];
  const float* bmv   = (const float*)d_in[17];
  const float* b_out = (const float*)d_in[18];
  float* out = (float*)d_out;

  float* ws = (float*)d_ws;
  size_t off = 0;
  auto alloc = [&](size_t n){ float* p = ws + off; off += (n + 63) & ~(size_t)63; return p; };

  short* WiPh_e   = (short*)alloc(262144);   // 2048*256 bf16
  short* WiPh_w   = (short*)alloc(262144);
  float* biasP_e  = alloc(2048);
  float* biasP_w  = alloc(2048);
  short* WhPh_e   = (short*)alloc(524288);   // 2048*512 bf16
  short* WhPh_w   = (short*)alloc(524288);
  short* Xp_e     = (short*)alloc(3276800);  // 3200*2048 bf16
  short* Xp_w     = (short*)alloc(3276800);
  ull*   hq       = (ull*)alloc(101*8192*2); // 101 step buffers x 64KB
  unsigned* flags = (unsigned*)alloc(128);   // block flags + fence slot
  float* Pbuf     = alloc(409600);           // 3200*128 f32 scores
  short* Pbh      = (short*)alloc(204800);   // 3200*128 bf16 softmax
  int*   ctr_del  = (int*)alloc(3168);
  int*   ctr_ins  = (int*)alloc(3168);
  short* Wph      = (short*)alloc(131072);   // 512*512 bf16
  short* Wmh      = (short*)alloc(262144);   // 256*2048 bf16
  short* keyh     = (short*)alloc(819200);   // 3200*512 bf16
  short* appliedh = (short*)alloc(819200);   // 3200*512 bf16
  short* ench     = (short*)alloc(819200);   // 32*100*512 bf16
  short* encTh    = (short*)alloc(1048576);  // 32*512*128 bf16
  short* embh     = (short*)alloc(3840000);  // 30000*256 bf16
  short* logith   = (short*)alloc(47520000); // 3168*30000 bf16 logits
  float2* partial = (float2*)alloc(3168*NTIL*2);
  // overlays (lifetimes disjoint, stream-ordered):
  short* feath    = (short*)Xp_e;            // 3168*2048 bf16, after recurrence
  short* hmlph    = (short*)Xp_w;            // 3168*256 bf16, after MLP

  // 1) ALL prep in one launch
  prep_all<<<16525, 256, 0, stream>>>(
      Wi_e, Wh_e, bi_e, bh_e, Wi_w, Wh_w, bi_w, bh_w,
      emb, Wp, Wm, h0, input_edits, enc,
      WiPh_e, WhPh_e, biasP_e, WiPh_w, WhPh_w, biasP_w,
      embh, Wph, Wmh, hq, flags, ctr_del, ctr_ins, ench, encTh);

  // 2) Xproj both LSTMs, one launch, bf16 out
  xproj_mfma<<<dim3(25,16,2), 256, 0, stream>>>(
      emb, input_edits, simp_sent, WiPh_e, WiPh_w, biasP_e, biasP_w, Xp_e, Xp_w);

  // 3) recurrence: persistent, block producer flags, hq-only output
  lstm_persist<<<LSTM_BLOCKS, 256, 0, stream>>>(
      WhPh_e, WhPh_w, Xp_e, Xp_w, c0, hq, out + 95040000L, flags);

  // 4) key = hq(out_e) @ Wp^T  (MFMA, HQ addressing, bf16 out)
  gemm_mfma<0,0,0,0,1,1><<<dim3(25,4), 256, 0, stream>>>(
      hq, nullptr, Wph, nullptr, keyh, 3200, 512, 512, 0 /*sel=e*/, 512);

  // 5) attention (all MFMA): scores -> softmax(bf16) -> applied(bf16)
  gemm_mfma_bat<0,0,0><<<dim3(1,1,32), 256, 0, stream>>>(
      keyh, ench, nullptr, Pbuf, 100, 100, 512, 512, 128,
      51200, 51200, 12800);
  softmax_rows<<<800, 256, 0, stream>>>(Pbuf, Pbh);
  gemm_mfma_bat<0,0,1><<<dim3(1,4,32), 256, 0, stream>>>(
      Pbh, encTh, nullptr, appliedh, 100, 512, 128, 128, 512,
      12800, 65536, 51200);

  // 6) feat (reads hq directly for out_e/out_w) + MLP (MFMA, tanh, bf16 out)
  feat_kernel<<<3168, 256, 0, stream>>>((const short*)hq, appliedh, ench,
                                        ctr_del, ctr_ins, feath);
  gemm_mfma<0,0,1,1,1,0><<<dim3(25,2), 256, 0, stream>>>(
      feath, nullptr, Wmh, bmv, hmlph, 3168, 256, 2048, 2048, 256);

  // 7) logits (MFMA, all-bf16, LSE partials) + fused log-softmax subtract
  logits_mfma_partial<<<dim3(25, NTIL), 256, 0, stream>>>(
      hmlph, embh, b_out, logith, partial);
  sub_lse_fused<<<3168, 256, 0, stream>>>(logith, partial, out);
}